// Round 2
// baseline (1380.198 us; speedup 1.0000x reference)
//
#include <hip/hip_runtime.h>
#include <stdint.h>

#define MDIM 8192
#define NDIM 11008
#define KDIM 4096
// fallback tile (old structure)
#define BM 128
#define BN 128
#define BK 32

typedef __bf16 bf16x8 __attribute__((ext_vector_type(8)));
typedef float floatx4 __attribute__((ext_vector_type(4)));

typedef const __attribute__((address_space(1))) void* gas_ptr;
typedef __attribute__((address_space(3))) void* las_ptr;

__device__ __forceinline__ unsigned short f32_bf16_rne(float f) {
    union { float f; unsigned u; } v; v.f = f;
    unsigned r = 0x7FFFu + ((v.u >> 16) & 1u);
    return (unsigned short)((v.u + r) >> 16);
}

// ---- pass 1: x fp32 -> bf16, 8 elems/thread ----
__global__ __launch_bounds__(256) void convert_x_kernel(
    const float* __restrict__ x, unsigned short* __restrict__ xb)
{
    const size_t gid = (size_t)blockIdx.x * 256 + threadIdx.x;
    const float4* p = (const float4*)x + gid * 2;
    float4 a = p[0], b = p[1];
    unsigned short t[8];
    t[0] = f32_bf16_rne(a.x); t[1] = f32_bf16_rne(a.y);
    t[2] = f32_bf16_rne(a.z); t[3] = f32_bf16_rne(a.w);
    t[4] = f32_bf16_rne(b.x); t[5] = f32_bf16_rne(b.y);
    t[6] = f32_bf16_rne(b.z); t[7] = f32_bf16_rne(b.w);
    *(uint4*)(xb + gid * 8) = *(const uint4*)t;
}

// ---- pass 2: qweight int32 -> dequantized bf16, 8 elems/thread ----
__global__ __launch_bounds__(256) void dequant_w_kernel(
    const int* __restrict__ q, const float* __restrict__ scales,
    const float* __restrict__ zps, unsigned short* __restrict__ wb)
{
    const size_t gid = (size_t)blockIdx.x * 256 + threadIdx.x;
    const int o = (int)(gid >> 9);           // 512 groups of 8 per row of 4096
    const float s = scales[o], z = zps[o];
    const int4* p = (const int4*)q + gid * 2;
    int4 a = p[0], b = p[1];
    unsigned short t[8];
    t[0] = f32_bf16_rne(((float)a.x - z) * s);
    t[1] = f32_bf16_rne(((float)a.y - z) * s);
    t[2] = f32_bf16_rne(((float)a.z - z) * s);
    t[3] = f32_bf16_rne(((float)a.w - z) * s);
    t[4] = f32_bf16_rne(((float)b.x - z) * s);
    t[5] = f32_bf16_rne(((float)b.y - z) * s);
    t[6] = f32_bf16_rne(((float)b.z - z) * s);
    t[7] = f32_bf16_rne(((float)b.w - z) * s);
    *(uint4*)(wb + gid * 8) = *(const uint4*)t;
}

// Arrive-only barrier. sched_barrier(0) pins instruction order at compile
// time WITHOUT memory semantics -> the compiler emits no s_waitcnt drain.
// (Round-1 lesson: asm volatile(""::: "memory") around s_barrier forces
// `s_waitcnt vmcnt(0)` before each barrier -- the asm "may read" the LDS
// that outstanding global_load_lds DMAs write -- silently destroying the
// counted-vmcnt pipeline. MfmaUtil stuck at 36%.)
__device__ __forceinline__ void pipe_barrier() {
    __builtin_amdgcn_sched_barrier(0);
    __builtin_amdgcn_s_barrier();
    __builtin_amdgcn_sched_barrier(0);
}

// ---- pass 3: 256x256 tile, BK=32, 4-buffer counted-vmcnt pipeline ----
// A[M,K] bf16, B[N,K] bf16, C[M,N] fp32 = A*B^T + bias.
// 8 waves (2M x 4N), per-wave 128x64 output, acc = floatx4[8][4].
// LDS: 4 buffers x (A 16KB + B 16KB) = 128 KiB (dynamic), 1 block/CU.
// Pipeline: while computing tile t (buf t&3), stage tile t+3 into buf
// (t+3)&3, which holds tile t-1 whose frag reads were lgkm-complete before
// tile t-1's closing barrier -> DMA can land anytime, race-free with
// arrive-only barriers (no drains needed).
// vmcnt(8) once per tile: 12 loads outstanding, confirms oldest 4 = tile
// t+1's slices (per-wave count; the following barrier makes it cross-wave).
// Never vmcnt(0) in the loop.
// LDS swizzle: 16B chunk c of row r stored at slot c ^ ((r>>1)&3); inverse
// applied on the global source so the LDS destination stays linear
// (global_load_lds rule). ds_read_b128 2-way bank aliasing only (free).
__global__ __launch_bounds__(512, 2) void gemm_bf16_pipe(
    const unsigned short* __restrict__ A,
    const unsigned short* __restrict__ B,
    const float* __restrict__ bias,
    float* __restrict__ C)
{
    extern __shared__ unsigned short lds[];   // 4 * 16384 ushorts

    const int tid  = threadIdx.x;
    const int lane = tid & 63;
    const int wave = tid >> 6;                // 0..7
    const int wm   = (wave >> 2) * 128;       // 0 or 128
    const int wn   = (wave & 3) * 64;         // 0,64,128,192

    // bijective XCD swizzle: 1376 wgs = 8 xcds * 172; each XCD walks full-M
    // columns (nt advances every 32) so its 2MB B-panel stays L2-resident.
    const int wg = blockIdx.x;
    const int f  = (wg & 7) * 172 + (wg >> 3);
    const int mt = f & 31;
    const int nt = f >> 5;
    const size_t bm = (size_t)mt * 256;
    const size_t bn = (size_t)nt * 256;

    const int mrow = lane & 15;
    const int kc   = lane >> 4;               // global 16B k-chunk 0..3
    const int gsw  = (mrow >> 1) & 3;
    const int ksw  = (kc ^ gsw) * 8;          // swizzled slot, elems
    const int offA = (wm + mrow) * 32 + ksw;            // + fi*512
    const int offB = 8192 + (wn + mrow) * 32 + ksw;     // + gi*512

    // staging source offsets (inverse swizzle applied on the global side;
    // LDS dest stays linear per global_load_lds contiguity rule)
    const int u0 = tid, u1 = tid + 512;
    const int r0 = u0 >> 2, c0 = (u0 & 3) ^ ((r0 >> 1) & 3);
    const int r1 = u1 >> 2, c1 = (u1 & 3) ^ ((r1 >> 1) & 3);
    const unsigned short* gA0 = A + (bm + r0) * KDIM + c0 * 8;
    const unsigned short* gA1 = A + (bm + r1) * KDIM + c1 * 8;
    const unsigned short* gB0 = B + (bn + r0) * KDIM + c0 * 8;
    const unsigned short* gB1 = B + (bn + r1) * KDIM + c1 * 8;
    const int dA0 = wave * 512, dA1 = 4096 + wave * 512;      // ushort offs
    const int dB0 = 8192 + wave * 512, dB1 = 12288 + wave * 512;

    floatx4 acc[8][4];
#pragma unroll
    for (int i = 0; i < 8; ++i)
#pragma unroll
        for (int j = 0; j < 4; ++j)
            acc[i][j] = (floatx4){0.f, 0.f, 0.f, 0.f};

    // prologue: stage tiles 0..2, confirm tile 0 (12 issued, keep 8 in flight)
#pragma unroll
    for (int tt = 0; tt < 3; ++tt) {
        unsigned short* sp = lds + tt * 16384;
        const int ko = tt * 32;
        __builtin_amdgcn_global_load_lds((gas_ptr)(gA0 + ko), (las_ptr)(sp + dA0), 16, 0, 0);
        __builtin_amdgcn_global_load_lds((gas_ptr)(gA1 + ko), (las_ptr)(sp + dA1), 16, 0, 0);
        __builtin_amdgcn_global_load_lds((gas_ptr)(gB0 + ko), (las_ptr)(sp + dB0), 16, 0, 0);
        __builtin_amdgcn_global_load_lds((gas_ptr)(gB1 + ko), (las_ptr)(sp + dB1), 16, 0, 0);
    }
    __builtin_amdgcn_sched_barrier(0);
    asm volatile("s_waitcnt vmcnt(8)");
    pipe_barrier();

    for (int tb = 0; tb < 128; tb += 4) {
#pragma unroll
        for (int q = 0; q < 4; ++q) {
            const int t = tb + q;
            const unsigned short* bp = lds + q * 16384;           // compute buf
            unsigned short* sp = lds + ((q + 3) & 3) * 16384;     // stage buf
            int pre = t + 3; if (pre > 127) pre = 127;  // tail: harmless re-stage
            const int ko = pre * 32;

            bf16x8 af[8], bfr[4];
            // ---- phase A: frags M0-3 x N0-3 ----
#pragma unroll
            for (int i = 0; i < 4; ++i)
                af[i] = *(const bf16x8*)(bp + offA + i * 512);
#pragma unroll
            for (int j = 0; j < 4; ++j)
                bfr[j] = *(const bf16x8*)(bp + offB + j * 512);
            __builtin_amdgcn_global_load_lds((gas_ptr)(gA0 + ko), (las_ptr)(sp + dA0), 16, 0, 0);
            __builtin_amdgcn_global_load_lds((gas_ptr)(gA1 + ko), (las_ptr)(sp + dA1), 16, 0, 0);
            pipe_barrier();
            __builtin_amdgcn_s_setprio(1);
#pragma unroll
            for (int i = 0; i < 4; ++i)
#pragma unroll
                for (int j = 0; j < 4; ++j)
                    acc[i][j] = __builtin_amdgcn_mfma_f32_16x16x32_bf16(
                        af[i], bfr[j], acc[i][j], 0, 0, 0);
            __builtin_amdgcn_s_setprio(0);
            pipe_barrier();
            // ---- phase B: frags M4-7 x N0-3 (B-frags reused in regs) ----
#pragma unroll
            for (int i = 4; i < 8; ++i)
                af[i] = *(const bf16x8*)(bp + offA + i * 512);
            __builtin_amdgcn_global_load_lds((gas_ptr)(gB0 + ko), (las_ptr)(sp + dB0), 16, 0, 0);
            __builtin_amdgcn_global_load_lds((gas_ptr)(gB1 + ko), (las_ptr)(sp + dB1), 16, 0, 0);
            __builtin_amdgcn_sched_barrier(0);
            asm volatile("s_waitcnt vmcnt(8)");   // confirm tile t+1 (own slices)
            pipe_barrier();
            __builtin_amdgcn_s_setprio(1);
#pragma unroll
            for (int i = 4; i < 8; ++i)
#pragma unroll
                for (int j = 0; j < 4; ++j)
                    acc[i][j] = __builtin_amdgcn_mfma_f32_16x16x32_bf16(
                        af[i], bfr[j], acc[i][j], 0, 0, 0);
            __builtin_amdgcn_s_setprio(0);
            pipe_barrier();
        }
    }
    __builtin_amdgcn_sched_barrier(0);
    asm volatile("s_waitcnt vmcnt(0)");  // drain tail re-stages before endpgm
    __builtin_amdgcn_sched_barrier(0);

    // epilogue: C/D layout col=lane&15, row=(lane>>4)*4+reg; NT stores keep
    // the 360MB C stream from evicting A/B out of L2/L3.
#pragma unroll
    for (int j = 0; j < 4; ++j) {
        const int col = (int)bn + wn + j * 16 + mrow;
        const float bv = bias[col];
#pragma unroll
        for (int i = 0; i < 8; ++i) {
            const size_t rbase = bm + wm + i * 16 + (lane >> 4) * 4;
#pragma unroll
            for (int r = 0; r < 4; ++r)
                __builtin_nontemporal_store(acc[i][j][r] + bv,
                                            &C[(rbase + r) * NDIM + col]);
        }
    }
}

// ---- fallback if ws too small: same tile structure, register-staged dequant ----
__global__ __launch_bounds__(256) void gemm_fused_fallback(
    const float* __restrict__ X, const int* __restrict__ Q,
    const float* __restrict__ scales, const float* __restrict__ zps,
    const float* __restrict__ bias, float* __restrict__ C)
{
    __shared__ __align__(16) unsigned short As[BM * BK];
    __shared__ __align__(16) unsigned short Bs[BN * BK];

    const int tid  = threadIdx.x;
    const int lane = tid & 63;
    const int wave = tid >> 6;
    const int wm   = (wave >> 1) * 64;
    const int wn   = (wave & 1) * 64;
    const int bm   = blockIdx.x * BM;
    const int bn   = blockIdx.y * BN;

    floatx4 acc[4][4];
#pragma unroll
    for (int i = 0; i < 4; ++i)
#pragma unroll
        for (int j = 0; j < 4; ++j)
            acc[i][j] = (floatx4){0.f, 0.f, 0.f, 0.f};

    const int mrow = lane & 15;
    const int kq   = (lane >> 4) * 8;

    for (int kt = 0; kt < KDIM; kt += BK) {
#pragma unroll
        for (int s4 = 0; s4 < 4; ++s4) {
            const int c = tid + 256 * s4;
            const int row = c >> 3, kcb = (c & 7) * 4;
            float4 xv = *(const float4*)(X + (size_t)(bm + row) * KDIM + kt + kcb);
            unsigned short ta[4];
            ta[0] = f32_bf16_rne(xv.x); ta[1] = f32_bf16_rne(xv.y);
            ta[2] = f32_bf16_rne(xv.z); ta[3] = f32_bf16_rne(xv.w);
            *(uint2*)(As + row * BK + kcb) = *(const uint2*)ta;

            int4 qv = *(const int4*)(Q + (size_t)(bn + row) * KDIM + kt + kcb);
            const float sc = scales[bn + row], z = zps[bn + row];
            unsigned short tb[4];
            tb[0] = f32_bf16_rne(((float)qv.x - z) * sc);
            tb[1] = f32_bf16_rne(((float)qv.y - z) * sc);
            tb[2] = f32_bf16_rne(((float)qv.z - z) * sc);
            tb[3] = f32_bf16_rne(((float)qv.w - z) * sc);
            *(uint2*)(Bs + row * BK + kcb) = *(const uint2*)tb;
        }
        __syncthreads();

        bf16x8 af[4], bfr[4];
#pragma unroll
        for (int i = 0; i < 4; ++i)
            af[i] = *(const bf16x8*)(As + (wm + i * 16 + mrow) * BK + kq);
#pragma unroll
        for (int j = 0; j < 4; ++j)
            bfr[j] = *(const bf16x8*)(Bs + (wn + j * 16 + mrow) * BK + kq);
#pragma unroll
        for (int i = 0; i < 4; ++i)
#pragma unroll
            for (int j = 0; j < 4; ++j)
                acc[i][j] = __builtin_amdgcn_mfma_f32_16x16x32_bf16(
                    af[i], bfr[j], acc[i][j], 0, 0, 0);
        __syncthreads();
    }

#pragma unroll
    for (int j = 0; j < 4; ++j) {
        const int col = bn + wn + j * 16 + mrow;
        const float bv = bias[col];
#pragma unroll
        for (int i = 0; i < 4; ++i) {
            const int rbase = bm + wm + i * 16 + (lane >> 4) * 4;
#pragma unroll
            for (int r = 0; r < 4; ++r)
                C[(size_t)(rbase + r) * NDIM + col] = acc[i][j][r] + bv;
        }
    }
}

extern "C" void kernel_launch(void* const* d_in, const int* in_sizes, int n_in,
                              void* d_out, int out_size, void* d_ws, size_t ws_size,
                              hipStream_t stream) {
    const float* x  = (const float*)d_in[0];
    const int*   qw = (const int*)d_in[1];
    const float* sc = (const float*)d_in[2];
    const float* zp = (const float*)d_in[3];
    const float* bs = (const float*)d_in[4];
    float* out = (float*)d_out;

    const size_t needA = (size_t)MDIM * KDIM * sizeof(unsigned short); // 64 MiB
    const size_t needW = (size_t)NDIM * KDIM * sizeof(unsigned short); // 86 MiB

    if (ws_size >= needA + needW) {
        static bool attr_set = false;
        if (!attr_set) {
            hipFuncSetAttribute(reinterpret_cast<const void*>(gemm_bf16_pipe),
                                hipFuncAttributeMaxDynamicSharedMemorySize, 131072);
            attr_set = true;
        }
        unsigned short* xb = (unsigned short*)d_ws;
        unsigned short* wb = (unsigned short*)((char*)d_ws + needA);
        convert_x_kernel<<<dim3(MDIM * KDIM / (8 * 256)), dim3(256), 0, stream>>>(x, xb);
        dequant_w_kernel<<<dim3(NDIM * KDIM / (8 * 256)), dim3(256), 0, stream>>>(qw, sc, zp, wb);
        gemm_bf16_pipe<<<dim3((MDIM / 256) * (NDIM / 256)), dim3(512), 131072, stream>>>(
            xb, wb, bs, out);
    } else {
        dim3 grid(MDIM / BM, NDIM / BN);
        gemm_fused_fallback<<<grid, dim3(256), 0, stream>>>(x, qw, sc, zp, bs, out);
    }
}

// Round 4
// 1312.267 us; speedup vs baseline: 1.0518x; 1.0518x over previous
//
#include <hip/hip_runtime.h>
#include <stdint.h>

#define MDIM 8192
#define NDIM 11008
#define KDIM 4096
// fallback tile (old structure)
#define BM 128
#define BN 128
#define BK 32

typedef __bf16 bf16x8 __attribute__((ext_vector_type(8)));
typedef float floatx4 __attribute__((ext_vector_type(4)));

typedef const __attribute__((address_space(1))) void* gas_ptr;
typedef __attribute__((address_space(3))) void* las_ptr;

__device__ __forceinline__ unsigned short f32_bf16_rne(float f) {
    union { float f; unsigned u; } v; v.f = f;
    unsigned r = 0x7FFFu + ((v.u >> 16) & 1u);
    return (unsigned short)((v.u + r) >> 16);
}

// ---- pass 1: x fp32 -> bf16, 8 elems/thread ----
__global__ __launch_bounds__(256) void convert_x_kernel(
    const float* __restrict__ x, unsigned short* __restrict__ xb)
{
    const size_t gid = (size_t)blockIdx.x * 256 + threadIdx.x;
    const float4* p = (const float4*)x + gid * 2;
    float4 a = p[0], b = p[1];
    unsigned short t[8];
    t[0] = f32_bf16_rne(a.x); t[1] = f32_bf16_rne(a.y);
    t[2] = f32_bf16_rne(a.z); t[3] = f32_bf16_rne(a.w);
    t[4] = f32_bf16_rne(b.x); t[5] = f32_bf16_rne(b.y);
    t[6] = f32_bf16_rne(b.z); t[7] = f32_bf16_rne(b.w);
    *(uint4*)(xb + gid * 8) = *(const uint4*)t;
}

// ---- pass 2: qweight int32 -> dequantized bf16, 8 elems/thread ----
__global__ __launch_bounds__(256) void dequant_w_kernel(
    const int* __restrict__ q, const float* __restrict__ scales,
    const float* __restrict__ zps, unsigned short* __restrict__ wb)
{
    const size_t gid = (size_t)blockIdx.x * 256 + threadIdx.x;
    const int o = (int)(gid >> 9);           // 512 groups of 8 per row of 4096
    const float s = scales[o], z = zps[o];
    const int4* p = (const int4*)q + gid * 2;
    int4 a = p[0], b = p[1];
    unsigned short t[8];
    t[0] = f32_bf16_rne(((float)a.x - z) * s);
    t[1] = f32_bf16_rne(((float)a.y - z) * s);
    t[2] = f32_bf16_rne(((float)a.z - z) * s);
    t[3] = f32_bf16_rne(((float)a.w - z) * s);
    t[4] = f32_bf16_rne(((float)b.x - z) * s);
    t[5] = f32_bf16_rne(((float)b.y - z) * s);
    t[6] = f32_bf16_rne(((float)b.z - z) * s);
    t[7] = f32_bf16_rne(((float)b.w - z) * s);
    *(uint4*)(wb + gid * 8) = *(const uint4*)t;
}

// Arrive-only barrier, sched_barrier(0)-pinned (no memory semantics -> no
// compiler-emitted vmcnt drain; round-1/2 lesson).
__device__ __forceinline__ void pipe_barrier() {
    __builtin_amdgcn_sched_barrier(0);
    __builtin_amdgcn_s_barrier();
    __builtin_amdgcn_sched_barrier(0);
}

// ---- pass 3: 256x256 tile, BK=32, 4-buffer pipeline, ONE barrier/K-tile ----
// Round-2 post-mortem: the intra-tile {reads -> barrier -> MFMA -> barrier}
// phases serialized the LDS pipe (96KB reads, ~900 cyc) against the MFMA
// pipe (1241 cyc) -> 3100 cyc/tile, MfmaUtil 37%. This version puts all 12
// frag reads + 4 DMA issues + 32 MFMAs in ONE barrier-free region: the
// compiler's fine-grained lgkmcnt waits let early MFMAs run while the LDS
// pipe serves later fragment reads (pipe overlap), targeting
// max(MFMA 1241, LDS ~1300) per tile instead of their sum.
// Race-freedom with one barrier/tile:
//  - reads of buffer q (tile t) are lgkm-complete before the wave's MFMAs,
//    hence before its barrier arrival; the DMA overwriting q (tile t+4)
//    issues after the NEXT barrier -> write-after-read safe.
//  - vmcnt(8) after the MFMAs (wait covered by compute) confirms tile t+1's
//    4 oldest DMAs per-wave; the tile barrier makes it cross-wave.
// LDS swizzle unchanged: chunk c of row r at slot c^((r>>1)&3), inverse on
// the global source, linear LDS dest (global_load_lds rule); 2-way bank
// aliasing only (free), SQ_LDS_BANK_CONFLICT == 0 measured.
__global__ __launch_bounds__(512, 2) void gemm_bf16_pipe(
    const unsigned short* __restrict__ A,
    const unsigned short* __restrict__ B,
    const float* __restrict__ bias,
    float* __restrict__ C)
{
    extern __shared__ unsigned short lds[];   // 4 * 16384 ushorts

    const int tid  = threadIdx.x;
    const int lane = tid & 63;
    const int wave = tid >> 6;                // 0..7
    const int wm   = (wave >> 2) * 128;       // 0 or 128
    const int wn   = (wave & 3) * 64;         // 0,64,128,192

    // bijective XCD swizzle: 1376 wgs = 8 xcds * 172; each XCD walks full-M
    // columns (nt advances every 32) so its 2MB B-panel stays L2-resident.
    const int wg = blockIdx.x;
    const int f  = (wg & 7) * 172 + (wg >> 3);
    const int mt = f & 31;
    const int nt = f >> 5;
    const size_t bm = (size_t)mt * 256;
    const size_t bn = (size_t)nt * 256;

    const int mrow = lane & 15;
    const int kc   = lane >> 4;               // global 16B k-chunk 0..3
    const int gsw  = (mrow >> 1) & 3;
    const int ksw  = (kc ^ gsw) * 8;          // swizzled slot, elems
    const int offA = (wm + mrow) * 32 + ksw;            // + fi*512
    const int offB = 8192 + (wn + mrow) * 32 + ksw;     // + gi*512

    // staging source offsets (inverse swizzle on the global side)
    const int u0 = tid, u1 = tid + 512;
    const int r0 = u0 >> 2, c0 = (u0 & 3) ^ ((r0 >> 1) & 3);
    const int r1 = u1 >> 2, c1 = (u1 & 3) ^ ((r1 >> 1) & 3);
    const unsigned short* gA0 = A + (bm + r0) * KDIM + c0 * 8;
    const unsigned short* gA1 = A + (bm + r1) * KDIM + c1 * 8;
    const unsigned short* gB0 = B + (bn + r0) * KDIM + c0 * 8;
    const unsigned short* gB1 = B + (bn + r1) * KDIM + c1 * 8;
    const int dA0 = wave * 512, dA1 = 4096 + wave * 512;      // ushort offs
    const int dB0 = 8192 + wave * 512, dB1 = 12288 + wave * 512;

    floatx4 acc[8][4];
#pragma unroll
    for (int i = 0; i < 8; ++i)
#pragma unroll
        for (int j = 0; j < 4; ++j)
            acc[i][j] = (floatx4){0.f, 0.f, 0.f, 0.f};

    // prologue: stage tiles 0..2 (12 loads), confirm tile 0 per-wave
#pragma unroll
    for (int tt = 0; tt < 3; ++tt) {
        unsigned short* sp = lds + tt * 16384;
        const int ko = tt * 32;
        __builtin_amdgcn_global_load_lds((gas_ptr)(gA0 + ko), (las_ptr)(sp + dA0), 16, 0, 0);
        __builtin_amdgcn_global_load_lds((gas_ptr)(gA1 + ko), (las_ptr)(sp + dA1), 16, 0, 0);
        __builtin_amdgcn_global_load_lds((gas_ptr)(gB0 + ko), (las_ptr)(sp + dB0), 16, 0, 0);
        __builtin_amdgcn_global_load_lds((gas_ptr)(gB1 + ko), (las_ptr)(sp + dB1), 16, 0, 0);
    }
    __builtin_amdgcn_sched_barrier(0);
    asm volatile("s_waitcnt vmcnt(8)");
    __builtin_amdgcn_sched_barrier(0);

    for (int tb = 0; tb < 128; tb += 4) {
#pragma unroll
        for (int q = 0; q < 4; ++q) {
            const int t = tb + q;
            const unsigned short* bp = lds + q * 16384;           // compute buf
            unsigned short* sp = lds + ((q + 3) & 3) * 16384;     // stage buf
            int pre = t + 3; if (pre > 127) pre = 127;  // tail: harmless re-stage
            const int ko = pre * 32;

            // tile-top barrier: buffer t confirmed (vmcnt at end of t-1),
            // buffer (q+3)&3 fully consumed (tile t-1's reads done pre-arrival)
            pipe_barrier();

            bf16x8 af[8], bfr[4];
#pragma unroll
            for (int i = 0; i < 4; ++i)
                af[i] = *(const bf16x8*)(bp + offA + i * 512);
#pragma unroll
            for (int j = 0; j < 4; ++j)
                bfr[j] = *(const bf16x8*)(bp + offB + j * 512);
#pragma unroll
            for (int i = 4; i < 8; ++i)
                af[i] = *(const bf16x8*)(bp + offA + i * 512);

            __builtin_amdgcn_global_load_lds((gas_ptr)(gA0 + ko), (las_ptr)(sp + dA0), 16, 0, 0);
            __builtin_amdgcn_global_load_lds((gas_ptr)(gA1 + ko), (las_ptr)(sp + dA1), 16, 0, 0);
            __builtin_amdgcn_global_load_lds((gas_ptr)(gB0 + ko), (las_ptr)(sp + dB0), 16, 0, 0);
            __builtin_amdgcn_global_load_lds((gas_ptr)(gB1 + ko), (las_ptr)(sp + dB1), 16, 0, 0);

            // MFMAs: compiler inserts partial lgkmcnt waits -> early MFMAs
            // overlap the LDS pipe serving later frag reads.
            __builtin_amdgcn_s_setprio(1);
#pragma unroll
            for (int i = 0; i < 4; ++i)
#pragma unroll
                for (int j = 0; j < 4; ++j)
                    acc[i][j] = __builtin_amdgcn_mfma_f32_16x16x32_bf16(
                        af[i], bfr[j], acc[i][j], 0, 0, 0);
#pragma unroll
            for (int i = 4; i < 8; ++i)
#pragma unroll
                for (int j = 0; j < 4; ++j)
                    acc[i][j] = __builtin_amdgcn_mfma_f32_16x16x32_bf16(
                        af[i], bfr[j], acc[i][j], 0, 0, 0);
            __builtin_amdgcn_s_setprio(0);

            // confirm tile t+1 (own 4 oldest of 12 outstanding); wait was
            // covered by the MFMA burst above.
            __builtin_amdgcn_sched_barrier(0);
            asm volatile("s_waitcnt vmcnt(8)");
            __builtin_amdgcn_sched_barrier(0);
        }
    }
    __builtin_amdgcn_sched_barrier(0);
    asm volatile("s_waitcnt vmcnt(0)");  // drain tail re-stages before endpgm
    __builtin_amdgcn_sched_barrier(0);

    // epilogue: C/D layout col=lane&15, row=(lane>>4)*4+reg; NT stores keep
    // the 360MB C stream from evicting A/B out of L2/L3.
#pragma unroll
    for (int j = 0; j < 4; ++j) {
        const int col = (int)bn + wn + j * 16 + mrow;
        const float bv = bias[col];
#pragma unroll
        for (int i = 0; i < 8; ++i) {
            const size_t rbase = bm + wm + i * 16 + (lane >> 4) * 4;
#pragma unroll
            for (int r = 0; r < 4; ++r)
                __builtin_nontemporal_store(acc[i][j][r] + bv,
                                            &C[(rbase + r) * NDIM + col]);
        }
    }
}

// ---- fallback if ws too small: same tile structure, register-staged dequant ----
__global__ __launch_bounds__(256) void gemm_fused_fallback(
    const float* __restrict__ X, const int* __restrict__ Q,
    const float* __restrict__ scales, const float* __restrict__ zps,
    const float* __restrict__ bias, float* __restrict__ C)
{
    __shared__ __align__(16) unsigned short As[BM * BK];
    __shared__ __align__(16) unsigned short Bs[BN * BK];

    const int tid  = threadIdx.x;
    const int lane = tid & 63;
    const int wave = tid >> 6;
    const int wm   = (wave >> 1) * 64;
    const int wn   = (wave & 1) * 64;
    const int bm   = blockIdx.x * BM;
    const int bn   = blockIdx.y * BN;

    floatx4 acc[4][4];
#pragma unroll
    for (int i = 0; i < 4; ++i)
#pragma unroll
        for (int j = 0; j < 4; ++j)
            acc[i][j] = (floatx4){0.f, 0.f, 0.f, 0.f};

    const int mrow = lane & 15;
    const int kq   = (lane >> 4) * 8;

    for (int kt = 0; kt < KDIM; kt += BK) {
#pragma unroll
        for (int s4 = 0; s4 < 4; ++s4) {
            const int c = tid + 256 * s4;
            const int row = c >> 3, kcb = (c & 7) * 4;
            float4 xv = *(const float4*)(X + (size_t)(bm + row) * KDIM + kt + kcb);
            unsigned short ta[4];
            ta[0] = f32_bf16_rne(xv.x); ta[1] = f32_bf16_rne(xv.y);
            ta[2] = f32_bf16_rne(xv.z); ta[3] = f32_bf16_rne(xv.w);
            *(uint2*)(As + row * BK + kcb) = *(const uint2*)ta;

            int4 qv = *(const int4*)(Q + (size_t)(bn + row) * KDIM + kt + kcb);
            const float sc = scales[bn + row], z = zps[bn + row];
            unsigned short tb[4];
            tb[0] = f32_bf16_rne(((float)qv.x - z) * sc);
            tb[1] = f32_bf16_rne(((float)qv.y - z) * sc);
            tb[2] = f32_bf16_rne(((float)qv.z - z) * sc);
            tb[3] = f32_bf16_rne(((float)qv.w - z) * sc);
            *(uint2*)(Bs + row * BK + kcb) = *(const uint2*)tb;
        }
        __syncthreads();

        bf16x8 af[4], bfr[4];
#pragma unroll
        for (int i = 0; i < 4; ++i)
            af[i] = *(const bf16x8*)(As + (wm + i * 16 + mrow) * BK + kq);
#pragma unroll
        for (int j = 0; j < 4; ++j)
            bfr[j] = *(const bf16x8*)(Bs + (wn + j * 16 + mrow) * BK + kq);
#pragma unroll
        for (int i = 0; i < 4; ++i)
#pragma unroll
            for (int j = 0; j < 4; ++j)
                acc[i][j] = __builtin_amdgcn_mfma_f32_16x16x32_bf16(
                    af[i], bfr[j], acc[i][j], 0, 0, 0);
        __syncthreads();
    }

#pragma unroll
    for (int j = 0; j < 4; ++j) {
        const int col = bn + wn + j * 16 + mrow;
        const float bv = bias[col];
#pragma unroll
        for (int i = 0; i < 4; ++i) {
            const int rbase = bm + wm + i * 16 + (lane >> 4) * 4;
#pragma unroll
            for (int r = 0; r < 4; ++r)
                C[(size_t)(rbase + r) * NDIM + col] = acc[i][j][r] + bv;
        }
    }
}

extern "C" void kernel_launch(void* const* d_in, const int* in_sizes, int n_in,
                              void* d_out, int out_size, void* d_ws, size_t ws_size,
                              hipStream_t stream) {
    const float* x  = (const float*)d_in[0];
    const int*   qw = (const int*)d_in[1];
    const float* sc = (const float*)d_in[2];
    const float* zp = (const float*)d_in[3];
    const float* bs = (const float*)d_in[4];
    float* out = (float*)d_out;

    const size_t needA = (size_t)MDIM * KDIM * sizeof(unsigned short); // 64 MiB
    const size_t needW = (size_t)NDIM * KDIM * sizeof(unsigned short); // 86 MiB

    if (ws_size >= needA + needW) {
        static bool attr_set = false;
        if (!attr_set) {
            hipFuncSetAttribute(reinterpret_cast<const void*>(gemm_bf16_pipe),
                                hipFuncAttributeMaxDynamicSharedMemorySize, 131072);
            attr_set = true;
        }
        unsigned short* xb = (unsigned short*)d_ws;
        unsigned short* wb = (unsigned short*)((char*)d_ws + needA);
        convert_x_kernel<<<dim3(MDIM * KDIM / (8 * 256)), dim3(256), 0, stream>>>(x, xb);
        dequant_w_kernel<<<dim3(NDIM * KDIM / (8 * 256)), dim3(256), 0, stream>>>(qw, sc, zp, wb);
        gemm_bf16_pipe<<<dim3((MDIM / 256) * (NDIM / 256)), dim3(512), 131072, stream>>>(
            xb, wb, bs, out);
    } else {
        dim3 grid(MDIM / BM, NDIM / BN);
        gemm_fused_fallback<<<grid, dim3(256), 0, stream>>>(x, qw, sc, zp, bs, out);
    }
}